// Round 1
// baseline (882.747 us; speedup 1.0000x reference)
//
#include <hip/hip_runtime.h>

typedef _Float16 f16x8 __attribute__((ext_vector_type(8)));
typedef float    f32x4 __attribute__((ext_vector_type(4)));

#define NC   64
#define NHW  65536

// ---------------------------------------------------------------------------
// K1: fused QKV 1x1-conv projection. fp32 in, fp16 out (to workspace).
// Thread = one pixel (b,h,w); 64 channels held in VGPRs; weights are
// wave-uniform loads (expected to compile to s_load).
// ---------------------------------------------------------------------------
__global__ __launch_bounds__(256) void proj_qkv(
    const float* __restrict__ x,
    const float* __restrict__ wq, const float* __restrict__ bq,
    const float* __restrict__ wk, const float* __restrict__ bk,
    const float* __restrict__ wv, const float* __restrict__ bv,
    _Float16* __restrict__ Qh, _Float16* __restrict__ Kh, _Float16* __restrict__ Vh)
{
    const int tid = threadIdx.x;
    const int b   = blockIdx.x >> 8;                 // 256 blocks per batch
    const int hw  = ((blockIdx.x & 255) << 8) | tid;
    const size_t pbase = (size_t)b * NC * NHW + hw;

    float xv[NC];
#pragma unroll
    for (int c = 0; c < NC; ++c) xv[c] = x[pbase + (size_t)c * NHW];

    for (int o = 0; o < NC; ++o) {
        float aq = bq[o], ak = bk[o], av = bv[o];
#pragma unroll
        for (int c = 0; c < NC; ++c) {
            const float xc = xv[c];
            aq = fmaf(xc, wq[o * NC + c], aq);
            ak = fmaf(xc, wk[o * NC + c], ak);
            av = fmaf(xc, wv[o * NC + c], av);
        }
        const size_t oi = pbase + (size_t)o * NHW;   // (b*64+o)*65536 + hw
        Qh[oi] = (_Float16)aq;
        Kh[oi] = (_Float16)ak;
        Vh[oi] = (_Float16)av;
    }
}

// ---------------------------------------------------------------------------
// K2: fused attention per (b,c). 16 waves; wave (wr,wc) owns a 64x64 att tile.
// Phase 1: att = Q K^T via mfma_f32_16x16x32_f16 (Q,K chunks staged in LDS).
// Phase 2: att += sig(gamma)*I on the diagonal; softmax over h (per column g).
// Phase 3: P (fp16, 128KiB swizzled LDS) times V (staged transposed) -> out.
// LDS swizzle everywhere: byte ^= ((row&7)<<4)  (Vt uses (w&7)^((w>>3)&7)).
// ---------------------------------------------------------------------------
#define P_OFF 0        // 131072 B : P fp16 [256][256]
#define B_OFF 131072   //  16384 B : Q chunk | softmax partials | Vt chunk
#define K_OFF 147456   //  16384 B : K chunk

__global__ __launch_bounds__(1024, 4) void attn_rowsm(
    const _Float16* __restrict__ Qh, const _Float16* __restrict__ Kh,
    const _Float16* __restrict__ Vh, const float* __restrict__ gamma,
    float* __restrict__ out)
{
    __shared__ __align__(16) unsigned char lds[163840];

    const int tid  = threadIdx.x;
    const int lane = tid & 63;
    const int wid  = tid >> 6;
    const int wr   = wid >> 2;
    const int wc   = wid & 3;
    const int q4   = lane >> 4;
    const int l15  = lane & 15;
    const size_t base = (size_t)blockIdx.x << 16;    // (b*64+c) * 65536

    const f32x4 fzero = {0.f, 0.f, 0.f, 0.f};
    f32x4 acc[4][4];
#pragma unroll
    for (int i = 0; i < 4; ++i)
#pragma unroll
        for (int j = 0; j < 4; ++j) acc[i][j] = fzero;

    // ---------------- phase 1: att = Q K^T ----------------
    const int sh = tid >> 2;                 // staging row 0..255
    const int ss = tid & 3;                  // 16B slot 0..3
    const int soff = ((sh << 6) + (ss << 4)) ^ ((sh & 7) << 4);
    const size_t sg = base + (size_t)sh * 256 + ss * 8;

    for (int kc = 0; kc < 256; kc += 32) {
        __syncthreads();
        const uint4 qd = *(const uint4*)(Qh + sg + kc);
        const uint4 kd = *(const uint4*)(Kh + sg + kc);
        *(uint4*)(lds + B_OFF + soff) = qd;
        *(uint4*)(lds + K_OFF + soff) = kd;
        __syncthreads();

        f16x8 bf[4];
#pragma unroll
        for (int ni = 0; ni < 4; ++ni) {
            const int g = (wc << 6) + (ni << 4) + l15;
            bf[ni] = *(const f16x8*)(lds + K_OFF + (((g << 6) + (q4 << 4)) ^ ((g & 7) << 4)));
        }
#pragma unroll
        for (int mi = 0; mi < 4; ++mi) {
            const int h = (wr << 6) + (mi << 4) + l15;
            const f16x8 af = *(const f16x8*)(lds + B_OFF + (((h << 6) + (q4 << 4)) ^ ((h & 7) << 4)));
#pragma unroll
            for (int ni = 0; ni < 4; ++ni)
                acc[mi][ni] = __builtin_amdgcn_mfma_f32_16x16x32_f16(af, bf[ni], acc[mi][ni], 0, 0, 0);
        }
    }

    // ---------------- phase 2: diag add + softmax over h ----------------
    const float g_sig = 1.0f / (1.0f + __expf(-gamma[0]));
    if (wr == wc) {                          // diagonal tiles: h==g
        const int rn = l15 - (q4 << 2);
        if (rn >= 0 && rn < 4) {
#pragma unroll
            for (int mi = 0; mi < 4; ++mi) acc[mi][mi][rn] += g_sig;
        }
    }

    float* red = (float*)(lds + B_OFF);      // [4][256] partials
    float cmx[4], cinv[4];

    __syncthreads();                         // phase-1 LDS now dead
#pragma unroll
    for (int ni = 0; ni < 4; ++ni) {
        float m = -3.0e38f;
#pragma unroll
        for (int mi = 0; mi < 4; ++mi)
#pragma unroll
            for (int r = 0; r < 4; ++r) m = fmaxf(m, acc[mi][ni][r]);
        m = fmaxf(m, __shfl_xor(m, 16));
        m = fmaxf(m, __shfl_xor(m, 32));
        cmx[ni] = m;
        if (q4 == 0) red[wr * 256 + (wc << 6) + (ni << 4) + l15] = m;
    }
    __syncthreads();
#pragma unroll
    for (int ni = 0; ni < 4; ++ni) {
        const int col = (wc << 6) + (ni << 4) + l15;
        float m = red[col];
        m = fmaxf(m, red[256 + col]);
        m = fmaxf(m, red[512 + col]);
        m = fmaxf(m, red[768 + col]);
        cmx[ni] = m;
    }
    __syncthreads();                         // maxes consumed; reuse red for sums
#pragma unroll
    for (int ni = 0; ni < 4; ++ni) {
        float s = 0.f;
#pragma unroll
        for (int mi = 0; mi < 4; ++mi)
#pragma unroll
            for (int r = 0; r < 4; ++r) {
                const float e = __expf(acc[mi][ni][r] - cmx[ni]);
                acc[mi][ni][r] = e;
                s += e;
            }
        s += __shfl_xor(s, 16);
        s += __shfl_xor(s, 32);
        if (q4 == 0) red[wr * 256 + (wc << 6) + (ni << 4) + l15] = s;
    }
    __syncthreads();
#pragma unroll
    for (int ni = 0; ni < 4; ++ni) {
        const int col = (wc << 6) + (ni << 4) + l15;
        cinv[ni] = 1.0f / (red[col] + red[256 + col] + red[512 + col] + red[768 + col]);
    }

    // write normalized P to LDS (fp16, swizzled [256][256])
#pragma unroll
    for (int mi = 0; mi < 4; ++mi) {
        const int hbase = (wr << 6) + (mi << 4) + (q4 << 2);
#pragma unroll
        for (int r = 0; r < 4; ++r) {
            const int h  = hbase + r;
            const int hb = h << 9;           // h*512 bytes
            const int sw = (h & 7) << 4;
#pragma unroll
            for (int ni = 0; ni < 4; ++ni) {
                const int g = (wc << 6) + (ni << 4) + l15;
                *(_Float16*)(lds + P_OFF + ((hb + (g << 1)) ^ sw)) =
                    (_Float16)(acc[mi][ni][r] * cinv[ni]);
            }
        }
    }

    // ---------------- phase 3: out = P V ----------------
#pragma unroll
    for (int i = 0; i < 4; ++i)
#pragma unroll
        for (int j = 0; j < 4; ++j) acc[i][j] = fzero;

    const int gg = tid >> 5;                 // g within chunk 0..31
    const int wo = tid & 31;                 // w octet
    for (int gc = 0; gc < 256; gc += 32) {
        __syncthreads();                     // P written / prior Vt reads done
        const uint4 vd = *(const uint4*)(Vh + base + (size_t)(gc + gg) * 256 + wo * 8);
        const _Float16* ve = (const _Float16*)&vd;
#pragma unroll
        for (int j = 0; j < 8; ++j) {
            const int w  = (wo << 3) + j;
            const int fw = ((w & 7) ^ ((w >> 3) & 7)) << 4;
            *(_Float16*)(lds + B_OFF + (((w << 6) + (gg << 1)) ^ fw)) = ve[j];
        }
        __syncthreads();

        f16x8 bf[4];
#pragma unroll
        for (int ni = 0; ni < 4; ++ni) {
            const int w  = (wc << 6) + (ni << 4) + l15;
            const int fw = ((w & 7) ^ ((w >> 3) & 7)) << 4;
            bf[ni] = *(const f16x8*)(lds + B_OFF + (((w << 6) + (q4 << 4)) ^ fw));
        }
#pragma unroll
        for (int mi = 0; mi < 4; ++mi) {
            const int h = (wr << 6) + (mi << 4) + l15;
            const f16x8 af = *(const f16x8*)(lds + P_OFF +
                (((h << 9) + ((gc + (q4 << 3)) << 1)) ^ ((h & 7) << 4)));
#pragma unroll
            for (int ni = 0; ni < 4; ++ni)
                acc[mi][ni] = __builtin_amdgcn_mfma_f32_16x16x32_f16(af, bf[ni], acc[mi][ni], 0, 0, 0);
        }
    }

    // ---------------- store out (fp32) ----------------
    float* op = out + base;
#pragma unroll
    for (int mi = 0; mi < 4; ++mi) {
#pragma unroll
        for (int r = 0; r < 4; ++r) {
            const int h = (wr << 6) + (mi << 4) + (q4 << 2) + r;
#pragma unroll
            for (int ni = 0; ni < 4; ++ni) {
                const int w = (wc << 6) + (ni << 4) + l15;
                op[(h << 8) + w] = acc[mi][ni][r];
            }
        }
    }
}

// ---------------------------------------------------------------------------
extern "C" void kernel_launch(void* const* d_in, const int* in_sizes, int n_in,
                              void* d_out, int out_size, void* d_ws, size_t ws_size,
                              hipStream_t stream) {
    const float* x     = (const float*)d_in[0];
    const float* wq    = (const float*)d_in[1];
    const float* bq    = (const float*)d_in[2];
    const float* wk    = (const float*)d_in[3];
    const float* bk    = (const float*)d_in[4];
    const float* wv    = (const float*)d_in[5];
    const float* bv    = (const float*)d_in[6];
    const float* gamma = (const float*)d_in[7];
    float* out = (float*)d_out;

    // workspace: Q,K,V fp16, each 512*65536 elements = 64 MiB -> 192 MiB total
    _Float16* Qh = (_Float16*)d_ws;
    _Float16* Kh = Qh + (size_t)512 * 65536;
    _Float16* Vh = Kh + (size_t)512 * 65536;

    proj_qkv<<<2048, 256, 0, stream>>>(x, wq, bq, wk, bk, wv, bv, Qh, Kh, Vh);
    attn_rowsm<<<512, 1024, 0, stream>>>(Qh, Kh, Vh, gamma, out);
}

// Round 2
// 207.089 us; speedup vs baseline: 4.2626x; 4.2626x over previous
//
#include <hip/hip_runtime.h>

typedef _Float16 f16x8 __attribute__((ext_vector_type(8)));
typedef float    f32x4 __attribute__((ext_vector_type(4)));

// ---------------------------------------------------------------------------
// K1: fused QKV 1x1-conv projection as an MFMA GEMM.
//   D[o, px] = sum_c W[o,c] * x[c,px] + b[o],  o in [0,192) = {Q|K|V}x64ch.
// No LDS: W fragments persist in VGPRs (A operand), x loaded per-lane
// coalesced (B operand, full 64B lines), bias is the MFMA C-init.
// Block = 4 waves: (ow = o-half of 96 rows) x (pw = px-half of 32).
// Block covers 256 px via 4 tile iterations of 64 px. Grid = 2048.
// Fragment mapping (verified in K2): A/B lane l15 -> row, k = q4*8+j;
// D row = q4*4+r, col = l15.
// ---------------------------------------------------------------------------
__global__ __launch_bounds__(256) void proj_qkv_mfma(
    const float* __restrict__ x,
    const float* __restrict__ wq, const float* __restrict__ bq,
    const float* __restrict__ wk, const float* __restrict__ bk,
    const float* __restrict__ wv, const float* __restrict__ bv,
    _Float16* __restrict__ Qh, _Float16* __restrict__ Kh, _Float16* __restrict__ Vh)
{
    const int tid  = threadIdx.x;
    const int lane = tid & 63;
    const int wid  = tid >> 6;
    const int ow   = wid >> 1;       // o half: 6 o-tiles of 16 rows
    const int pw   = wid & 1;        // px half: 32 px
    const int q4   = lane >> 4;
    const int l15  = lane & 15;

    // ---- stationary weight fragments: 6 o-tiles x 2 k-chunks (48 VGPRs) ----
    f16x8 af[6][2];
#pragma unroll
    for (int t = 0; t < 6; ++t) {
        const int ot = ow * 6 + t;                    // 0..11
        const int m  = ot >> 2;                       // 0=Q 1=K 2=V
        const float* wsrcb = (m == 0) ? wq : (m == 1) ? wk : wv;
        const int row = ((ot & 3) << 4) + l15;        // 0..63 within matrix
#pragma unroll
        for (int kc = 0; kc < 2; ++kc) {
            const float* ws = wsrcb + row * 64 + (kc << 5) + (q4 << 3);
            const f32x4 w0 = *(const f32x4*)ws;
            const f32x4 w1 = *(const f32x4*)(ws + 4);
            f16x8 a;
#pragma unroll
            for (int j = 0; j < 4; ++j) { a[j] = (_Float16)w0[j]; a[4 + j] = (_Float16)w1[j]; }
            af[t][kc] = a;
        }
    }

    for (int tt = 0; tt < 4; ++tt) {
        const int pg  = (blockIdx.x << 8) + (tt << 6);   // global pixel base
        const int bb  = pg >> 16;                        // batch
        const int hw0 = (pg & 65535) + (pw << 5) + l15;  // this lane's px (+ps*16)
        const size_t xbase = ((size_t)bb << 22);         // bb*64*65536

        // ---- B fragments: 2 px-subtiles x 2 k-chunks, coalesced 64B lines ----
        f16x8 bf[2][2];
#pragma unroll
        for (int ps = 0; ps < 2; ++ps) {
#pragma unroll
            for (int kc = 0; kc < 2; ++kc) {
                const int hw = hw0 + (ps << 4);
                f16x8 v;
#pragma unroll
                for (int j = 0; j < 8; ++j) {
                    const int c = (kc << 5) + (q4 << 3) + j;
                    v[j] = (_Float16)x[xbase + ((size_t)c << 16) + hw];
                }
                bf[ps][kc] = v;
            }
        }

        // ---- per o-tile: bias-init acc, 4 MFMA, store fp16 ----
#pragma unroll
        for (int t = 0; t < 6; ++t) {
            const int ot = ow * 6 + t;
            const int m  = ot >> 2;
            const float* bsrc = (m == 0) ? bq : (m == 1) ? bk : bv;
            const f32x4 binit = *(const f32x4*)(bsrc + ((ot & 3) << 4) + (q4 << 2));
            f32x4 acc0 = binit, acc1 = binit;
            acc0 = __builtin_amdgcn_mfma_f32_16x16x32_f16(af[t][0], bf[0][0], acc0, 0, 0, 0);
            acc0 = __builtin_amdgcn_mfma_f32_16x16x32_f16(af[t][1], bf[0][1], acc0, 0, 0, 0);
            acc1 = __builtin_amdgcn_mfma_f32_16x16x32_f16(af[t][0], bf[1][0], acc1, 0, 0, 0);
            acc1 = __builtin_amdgcn_mfma_f32_16x16x32_f16(af[t][1], bf[1][1], acc1, 0, 0, 0);
            _Float16* obase = (m == 0) ? Qh : (m == 1) ? Kh : Vh;
            const int orow0 = ((ot & 3) << 4) + (q4 << 2);
#pragma unroll
            for (int r = 0; r < 4; ++r) {
                const size_t rowoff = ((size_t)(bb * 64 + orow0 + r) << 16);
                obase[rowoff + hw0]      = (_Float16)acc0[r];
                obase[rowoff + hw0 + 16] = (_Float16)acc1[r];
            }
        }
    }
}

// ---------------------------------------------------------------------------
// K2: fused attention per (b,c). 16 waves; wave (wr,wc) owns a 64x64 att tile.
// Phase 1: att = Q K^T via mfma_f32_16x16x32_f16 (Q,K chunks staged in LDS).
// Phase 2: att += sig(gamma)*I on the diagonal; softmax over h (per column g).
// Phase 3: P (fp16, 128KiB swizzled LDS) times V (staged transposed) -> out.
// LDS swizzle everywhere: byte ^= ((row&7)<<4)  (Vt uses (w&7)^((w>>3)&7)).
// Already at its memory floor (~335 MB -> ~54 us); unchanged this round.
// ---------------------------------------------------------------------------
#define P_OFF 0        // 131072 B : P fp16 [256][256]
#define B_OFF 131072   //  16384 B : Q chunk | softmax partials | Vt chunk
#define K_OFF 147456   //  16384 B : K chunk

__global__ __launch_bounds__(1024, 4) void attn_rowsm(
    const _Float16* __restrict__ Qh, const _Float16* __restrict__ Kh,
    const _Float16* __restrict__ Vh, const float* __restrict__ gamma,
    float* __restrict__ out)
{
    __shared__ __align__(16) unsigned char lds[163840];

    const int tid  = threadIdx.x;
    const int lane = tid & 63;
    const int wid  = tid >> 6;
    const int wr   = wid >> 2;
    const int wc   = wid & 3;
    const int q4   = lane >> 4;
    const int l15  = lane & 15;
    const size_t base = (size_t)blockIdx.x << 16;    // (b*64+c) * 65536

    const f32x4 fzero = {0.f, 0.f, 0.f, 0.f};
    f32x4 acc[4][4];
#pragma unroll
    for (int i = 0; i < 4; ++i)
#pragma unroll
        for (int j = 0; j < 4; ++j) acc[i][j] = fzero;

    // ---------------- phase 1: att = Q K^T ----------------
    const int sh = tid >> 2;                 // staging row 0..255
    const int ss = tid & 3;                  // 16B slot 0..3
    const int soff = ((sh << 6) + (ss << 4)) ^ ((sh & 7) << 4);
    const size_t sg = base + (size_t)sh * 256 + ss * 8;

    for (int kc = 0; kc < 256; kc += 32) {
        __syncthreads();
        const uint4 qd = *(const uint4*)(Qh + sg + kc);
        const uint4 kd = *(const uint4*)(Kh + sg + kc);
        *(uint4*)(lds + B_OFF + soff) = qd;
        *(uint4*)(lds + K_OFF + soff) = kd;
        __syncthreads();

        f16x8 bf[4];
#pragma unroll
        for (int ni = 0; ni < 4; ++ni) {
            const int g = (wc << 6) + (ni << 4) + l15;
            bf[ni] = *(const f16x8*)(lds + K_OFF + (((g << 6) + (q4 << 4)) ^ ((g & 7) << 4)));
        }
#pragma unroll
        for (int mi = 0; mi < 4; ++mi) {
            const int h = (wr << 6) + (mi << 4) + l15;
            const f16x8 af = *(const f16x8*)(lds + B_OFF + (((h << 6) + (q4 << 4)) ^ ((h & 7) << 4)));
#pragma unroll
            for (int ni = 0; ni < 4; ++ni)
                acc[mi][ni] = __builtin_amdgcn_mfma_f32_16x16x32_f16(af, bf[ni], acc[mi][ni], 0, 0, 0);
        }
    }

    // ---------------- phase 2: diag add + softmax over h ----------------
    const float g_sig = 1.0f / (1.0f + __expf(-gamma[0]));
    if (wr == wc) {                          // diagonal tiles: h==g
        const int rn = l15 - (q4 << 2);
        if (rn >= 0 && rn < 4) {
#pragma unroll
            for (int mi = 0; mi < 4; ++mi) acc[mi][mi][rn] += g_sig;
        }
    }

    float* red = (float*)(lds + B_OFF);      // [4][256] partials
    float cmx[4], cinv[4];

    __syncthreads();                         // phase-1 LDS now dead
#pragma unroll
    for (int ni = 0; ni < 4; ++ni) {
        float m = -3.0e38f;
#pragma unroll
        for (int mi = 0; mi < 4; ++mi)
#pragma unroll
            for (int r = 0; r < 4; ++r) m = fmaxf(m, acc[mi][ni][r]);
        m = fmaxf(m, __shfl_xor(m, 16));
        m = fmaxf(m, __shfl_xor(m, 32));
        cmx[ni] = m;
        if (q4 == 0) red[wr * 256 + (wc << 6) + (ni << 4) + l15] = m;
    }
    __syncthreads();
#pragma unroll
    for (int ni = 0; ni < 4; ++ni) {
        const int col = (wc << 6) + (ni << 4) + l15;
        float m = red[col];
        m = fmaxf(m, red[256 + col]);
        m = fmaxf(m, red[512 + col]);
        m = fmaxf(m, red[768 + col]);
        cmx[ni] = m;
    }
    __syncthreads();                         // maxes consumed; reuse red for sums
#pragma unroll
    for (int ni = 0; ni < 4; ++ni) {
        float s = 0.f;
#pragma unroll
        for (int mi = 0; mi < 4; ++mi)
#pragma unroll
            for (int r = 0; r < 4; ++r) {
                const float e = __expf(acc[mi][ni][r] - cmx[ni]);
                acc[mi][ni][r] = e;
                s += e;
            }
        s += __shfl_xor(s, 16);
        s += __shfl_xor(s, 32);
        if (q4 == 0) red[wr * 256 + (wc << 6) + (ni << 4) + l15] = s;
    }
    __syncthreads();
#pragma unroll
    for (int ni = 0; ni < 4; ++ni) {
        const int col = (wc << 6) + (ni << 4) + l15;
        cinv[ni] = 1.0f / (red[col] + red[256 + col] + red[512 + col] + red[768 + col]);
    }

    // write normalized P to LDS (fp16, swizzled [256][256])
#pragma unroll
    for (int mi = 0; mi < 4; ++mi) {
        const int hbase = (wr << 6) + (mi << 4) + (q4 << 2);
#pragma unroll
        for (int r = 0; r < 4; ++r) {
            const int h  = hbase + r;
            const int hb = h << 9;           // h*512 bytes
            const int sw = (h & 7) << 4;
#pragma unroll
            for (int ni = 0; ni < 4; ++ni) {
                const int g = (wc << 6) + (ni << 4) + l15;
                *(_Float16*)(lds + P_OFF + ((hb + (g << 1)) ^ sw)) =
                    (_Float16)(acc[mi][ni][r] * cinv[ni]);
            }
        }
    }

    // ---------------- phase 3: out = P V ----------------
#pragma unroll
    for (int i = 0; i < 4; ++i)
#pragma unroll
        for (int j = 0; j < 4; ++j) acc[i][j] = fzero;

    const int gg = tid >> 5;                 // g within chunk 0..31
    const int wo = tid & 31;                 // w octet
    for (int gc = 0; gc < 256; gc += 32) {
        __syncthreads();                     // P written / prior Vt reads done
        const uint4 vd = *(const uint4*)(Vh + base + (size_t)(gc + gg) * 256 + wo * 8);
        const _Float16* ve = (const _Float16*)&vd;
#pragma unroll
        for (int j = 0; j < 8; ++j) {
            const int w  = (wo << 3) + j;
            const int fw = ((w & 7) ^ ((w >> 3) & 7)) << 4;
            *(_Float16*)(lds + B_OFF + (((w << 6) + (gg << 1)) ^ fw)) = ve[j];
        }
        __syncthreads();

        f16x8 bf[4];
#pragma unroll
        for (int ni = 0; ni < 4; ++ni) {
            const int w  = (wc << 6) + (ni << 4) + l15;
            const int fw = ((w & 7) ^ ((w >> 3) & 7)) << 4;
            bf[ni] = *(const f16x8*)(lds + B_OFF + (((w << 6) + (q4 << 4)) ^ fw));
        }
#pragma unroll
        for (int mi = 0; mi < 4; ++mi) {
            const int h = (wr << 6) + (mi << 4) + l15;
            const f16x8 af = *(const f16x8*)(lds + P_OFF +
                (((h << 9) + ((gc + (q4 << 3)) << 1)) ^ ((h & 7) << 4)));
#pragma unroll
            for (int ni = 0; ni < 4; ++ni)
                acc[mi][ni] = __builtin_amdgcn_mfma_f32_16x16x32_f16(af, bf[ni], acc[mi][ni], 0, 0, 0);
        }
    }

    // ---------------- store out (fp32) ----------------
    float* op = out + base;
#pragma unroll
    for (int mi = 0; mi < 4; ++mi) {
#pragma unroll
        for (int r = 0; r < 4; ++r) {
            const int h = (wr << 6) + (mi << 4) + (q4 << 2) + r;
#pragma unroll
            for (int ni = 0; ni < 4; ++ni) {
                const int w = (wc << 6) + (ni << 4) + l15;
                op[(h << 8) + w] = acc[mi][ni][r];
            }
        }
    }
}

// ---------------------------------------------------------------------------
extern "C" void kernel_launch(void* const* d_in, const int* in_sizes, int n_in,
                              void* d_out, int out_size, void* d_ws, size_t ws_size,
                              hipStream_t stream) {
    const float* x     = (const float*)d_in[0];
    const float* wq    = (const float*)d_in[1];
    const float* bq    = (const float*)d_in[2];
    const float* wk    = (const float*)d_in[3];
    const float* bk    = (const float*)d_in[4];
    const float* wv    = (const float*)d_in[5];
    const float* bv    = (const float*)d_in[6];
    const float* gamma = (const float*)d_in[7];
    float* out = (float*)d_out;

    // workspace: Q,K,V fp16, each 512*65536 elements = 64 MiB -> 192 MiB total
    _Float16* Qh = (_Float16*)d_ws;
    _Float16* Kh = Qh + (size_t)512 * 65536;
    _Float16* Vh = Kh + (size_t)512 * 65536;

    proj_qkv_mfma<<<2048, 256, 0, stream>>>(x, wq, bq, wk, bk, wv, bv, Qh, Kh, Vh);
    attn_rowsm<<<512, 1024, 0, stream>>>(Qh, Kh, Vh, gamma, out);
}

// Round 3
// 183.135 us; speedup vs baseline: 4.8202x; 1.1308x over previous
//
#include <hip/hip_runtime.h>

typedef _Float16 f16x8 __attribute__((ext_vector_type(8)));
typedef _Float16 f16x4 __attribute__((ext_vector_type(4)));
typedef float    f32x4 __attribute__((ext_vector_type(4)));

// ===========================================================================
// K1: QKV 1x1-conv projection as LDS-staged MFMA GEMM, computing
//   D[px, o] = sum_c x[c,px] * W[o,c] + b[o]   (x tile as A, weights as B).
// Key points:
//  - x tile (64c x 128px) and ALL weights (192o x 64c) staged fp16 in LDS via
//    coalesced float4 global loads + conflict-free 8B ds_writes (no transpose
//    on the write side). LDS = 40960B exactly -> 4 blocks/CU.
//  - Transpose on the LDS-READ side: A-fragments via 32 one-time ds_read_u16
//    gathers (lgkmcnt, NOT vmcnt -> no serialization against global stores).
//  - D rows = px (q4*4+r = 4 consecutive px per lane) -> packed 8B stores.
//  - Bias preloaded to regs before any store is issued.
// ===========================================================================
#define XT_OFF 0       // fp16 x [64c][128px], row 256B, swz ((c>>3)&7)<<4
#define W_OFF  16384   // fp16 w [192o][64c],  row 128B, swz (orow&7)<<4

__global__ __launch_bounds__(256, 4) void proj_qkv_mfma(
    const float* __restrict__ x,
    const float* __restrict__ wq, const float* __restrict__ bq,
    const float* __restrict__ wk, const float* __restrict__ bk,
    const float* __restrict__ wv, const float* __restrict__ bv,
    _Float16* __restrict__ Qh, _Float16* __restrict__ Kh, _Float16* __restrict__ Vh)
{
    __shared__ __align__(16) unsigned char lds[40960];

    const int tid  = threadIdx.x;
    const int lane = tid & 63;
    const int wid  = tid >> 6;
    const int q4   = lane >> 4;
    const int l15  = lane & 15;

    const int pg  = blockIdx.x << 7;          // 128 px per block
    const int bb  = pg >> 16;                 // batch
    const int pix = pg & 65535;               // pixel base within image
    const size_t xbase = ((size_t)bb << 22) + pix;

    // ---- bias preload (before any stores) ----
    float bld[12];
#pragma unroll
    for (int ot = 0; ot < 12; ++ot) {
        const int mat = ot >> 2;
        const float* bs = (mat == 0) ? bq : (mat == 1) ? bk : bv;
        bld[ot] = bs[((ot & 3) << 4) + l15];
    }

    // ---- stage x tile [64][128] f32 -> fp16 LDS ----
#pragma unroll
    for (int it = 0; it < 8; ++it) {
        const int idx = (it << 8) + tid;       // 0..2047 float4 slots
        const int c = idx >> 5;
        const int s = idx & 31;                // px = s*4
        const f32x4 v = *(const f32x4*)(x + xbase + (size_t)c * 65536 + (s << 2));
        f16x4 h;
#pragma unroll
        for (int j = 0; j < 4; ++j) h[j] = (_Float16)v[j];
        const int a = ((c << 8) + (s << 3)) ^ (((c >> 3) & 7) << 4);
        *(f16x4*)(lds + XT_OFF + a) = h;
    }

    // ---- stage weights [192][64] f32 -> fp16 LDS ----
#pragma unroll
    for (int it = 0; it < 12; ++it) {
        const int idx  = (it << 8) + tid;      // 0..3071 float4 slots
        const int orow = idx >> 4;
        const int s    = idx & 15;             // c = s*4
        const int mat  = orow >> 6;
        const float* wsrc = (mat == 0) ? wq : (mat == 1) ? wk : wv;
        const f32x4 v = *(const f32x4*)(wsrc + ((orow & 63) << 6) + (s << 2));
        f16x4 h;
#pragma unroll
        for (int j = 0; j < 4; ++j) h[j] = (_Float16)v[j];
        const int a = ((orow << 7) + (s << 3)) ^ ((orow & 7) << 4);
        *(f16x4*)(lds + W_OFF + a) = h;
    }

    __syncthreads();

    // ---- A fragments: lane l15 = px, k = c (one-time u16 gathers) ----
    const int wpx = wid << 5;                  // wave px base (32 px/wave)
    f16x8 af[2][2];
#pragma unroll
    for (int pt = 0; pt < 2; ++pt)
#pragma unroll
        for (int kc = 0; kc < 2; ++kc) {
            const int px = wpx + (pt << 4) + l15;
            f16x8 a;
#pragma unroll
            for (int j = 0; j < 8; ++j) {
                const int c  = (kc << 5) + (q4 << 3) + j;
                const int ad = ((c << 8) + (px << 1)) ^ (((c >> 3) & 7) << 4);
                a[j] = *(const _Float16*)(lds + XT_OFF + ad);
            }
            af[pt][kc] = a;
        }

    // ---- ot loop: B from LDS (lgkm), MFMA, packed 8B stores (vmcnt) ----
#pragma unroll
    for (int ot = 0; ot < 12; ++ot) {
        const int mat = ot >> 2;
        const int row = (ot << 4) + l15;       // B lane l15 = o col
        const int rsw = (row & 7) << 4;
        const f16x8 bf0 = *(const f16x8*)(lds + W_OFF + (((row << 7) + (q4 << 4)) ^ rsw));
        const f16x8 bf1 = *(const f16x8*)(lds + W_OFF + (((row << 7) + 64 + (q4 << 4)) ^ rsw));
        _Float16* ob = (mat == 0) ? Qh : (mat == 1) ? Kh : Vh;
        const int r64 = ((ot & 3) << 4) + l15;
        const size_t obase = ((size_t)((bb << 6) + r64) << 16) + pix + wpx + (q4 << 2);
#pragma unroll
        for (int pt = 0; pt < 2; ++pt) {
            f32x4 acc = { bld[ot], bld[ot], bld[ot], bld[ot] };
            acc = __builtin_amdgcn_mfma_f32_16x16x32_f16(af[pt][0], bf0, acc, 0, 0, 0);
            acc = __builtin_amdgcn_mfma_f32_16x16x32_f16(af[pt][1], bf1, acc, 0, 0, 0);
            f16x4 h;
#pragma unroll
            for (int r = 0; r < 4; ++r) h[r] = (_Float16)acc[r];
            *(f16x4*)(ob + obase + (pt << 4)) = h;   // 4 consecutive px
        }
    }
}

// ===========================================================================
// K2: fused attention per (b,c). 16 waves; wave (wr,wc) owns a 64x64 att tile.
// Round-2 change: register prefetch of the next Q/K (phase 1) and V (phase 3)
// chunk issued between the LDS-write and the MFMAs of the current chunk, so
// HBM latency hides under compute instead of sitting between barriers.
// ===========================================================================
#define P_OFF 0        // 131072 B : P fp16 [256][256]
#define B_OFF 131072   //  16384 B : Q chunk | softmax partials | Vt chunk
#define K_OFF 147456   //  16384 B : K chunk

__global__ __launch_bounds__(1024, 4) void attn_rowsm(
    const _Float16* __restrict__ Qh, const _Float16* __restrict__ Kh,
    const _Float16* __restrict__ Vh, const float* __restrict__ gamma,
    float* __restrict__ out)
{
    __shared__ __align__(16) unsigned char lds[163840];

    const int tid  = threadIdx.x;
    const int lane = tid & 63;
    const int wid  = tid >> 6;
    const int wr   = wid >> 2;
    const int wc   = wid & 3;
    const int q4   = lane >> 4;
    const int l15  = lane & 15;
    const size_t base = (size_t)blockIdx.x << 16;    // (b*64+c) * 65536

    const f32x4 fzero = {0.f, 0.f, 0.f, 0.f};
    f32x4 acc[4][4];
#pragma unroll
    for (int i = 0; i < 4; ++i)
#pragma unroll
        for (int j = 0; j < 4; ++j) acc[i][j] = fzero;

    // ---------------- phase 1: att = Q K^T (prefetched) ----------------
    const int sh = tid >> 2;                 // staging row 0..255
    const int ss = tid & 3;                  // 16B slot 0..3
    const int soff = ((sh << 6) + (ss << 4)) ^ ((sh & 7) << 4);
    const size_t sg = base + (size_t)sh * 256 + ss * 8;

    uint4 qd = *(const uint4*)(Qh + sg);
    uint4 kd = *(const uint4*)(Kh + sg);

    for (int kc = 0; kc < 256; kc += 32) {
        __syncthreads();                     // prior chunk's frag reads done
        *(uint4*)(lds + B_OFF + soff) = qd;
        *(uint4*)(lds + K_OFF + soff) = kd;
        if (kc < 224) {                      // issue next chunk early
            qd = *(const uint4*)(Qh + sg + kc + 32);
            kd = *(const uint4*)(Kh + sg + kc + 32);
        }
        __syncthreads();                     // writes visible

        f16x8 bf[4];
#pragma unroll
        for (int ni = 0; ni < 4; ++ni) {
            const int g = (wc << 6) + (ni << 4) + l15;
            bf[ni] = *(const f16x8*)(lds + K_OFF + (((g << 6) + (q4 << 4)) ^ ((g & 7) << 4)));
        }
#pragma unroll
        for (int mi = 0; mi < 4; ++mi) {
            const int h = (wr << 6) + (mi << 4) + l15;
            const f16x8 af = *(const f16x8*)(lds + B_OFF + (((h << 6) + (q4 << 4)) ^ ((h & 7) << 4)));
#pragma unroll
            for (int ni = 0; ni < 4; ++ni)
                acc[mi][ni] = __builtin_amdgcn_mfma_f32_16x16x32_f16(af, bf[ni], acc[mi][ni], 0, 0, 0);
        }
    }

    // ---------------- phase 2: diag add + softmax over h ----------------
    const float g_sig = 1.0f / (1.0f + __expf(-gamma[0]));
    if (wr == wc) {                          // diagonal tiles: h==g
        const int rn = l15 - (q4 << 2);
        if (rn >= 0 && rn < 4) {
#pragma unroll
            for (int mi = 0; mi < 4; ++mi) acc[mi][mi][rn] += g_sig;
        }
    }

    float* red = (float*)(lds + B_OFF);      // [4][256] partials
    float cmx[4], cinv[4];

    __syncthreads();                         // phase-1 LDS now dead
#pragma unroll
    for (int ni = 0; ni < 4; ++ni) {
        float m = -3.0e38f;
#pragma unroll
        for (int mi = 0; mi < 4; ++mi)
#pragma unroll
            for (int r = 0; r < 4; ++r) m = fmaxf(m, acc[mi][ni][r]);
        m = fmaxf(m, __shfl_xor(m, 16));
        m = fmaxf(m, __shfl_xor(m, 32));
        cmx[ni] = m;
        if (q4 == 0) red[wr * 256 + (wc << 6) + (ni << 4) + l15] = m;
    }
    __syncthreads();
#pragma unroll
    for (int ni = 0; ni < 4; ++ni) {
        const int col = (wc << 6) + (ni << 4) + l15;
        float m = red[col];
        m = fmaxf(m, red[256 + col]);
        m = fmaxf(m, red[512 + col]);
        m = fmaxf(m, red[768 + col]);
        cmx[ni] = m;
    }
    __syncthreads();                         // maxes consumed; reuse red for sums
#pragma unroll
    for (int ni = 0; ni < 4; ++ni) {
        float s = 0.f;
#pragma unroll
        for (int mi = 0; mi < 4; ++mi)
#pragma unroll
            for (int r = 0; r < 4; ++r) {
                const float e = __expf(acc[mi][ni][r] - cmx[ni]);
                acc[mi][ni][r] = e;
                s += e;
            }
        s += __shfl_xor(s, 16);
        s += __shfl_xor(s, 32);
        if (q4 == 0) red[wr * 256 + (wc << 6) + (ni << 4) + l15] = s;
    }
    __syncthreads();
#pragma unroll
    for (int ni = 0; ni < 4; ++ni) {
        const int col = (wc << 6) + (ni << 4) + l15;
        cinv[ni] = 1.0f / (red[col] + red[256 + col] + red[512 + col] + red[768 + col]);
    }

    // V chunk-0 prefetch: issue now, hides under P-writes + barrier
    const int gg = tid >> 5;                 // g within chunk 0..31
    const int wo = tid & 31;                 // w octet
    const size_t vg = base + (size_t)gg * 256 + wo * 8;
    uint4 vd = *(const uint4*)(Vh + vg);

    // write normalized P to LDS (fp16, swizzled [256][256])
#pragma unroll
    for (int mi = 0; mi < 4; ++mi) {
        const int hbase = (wr << 6) + (mi << 4) + (q4 << 2);
#pragma unroll
        for (int r = 0; r < 4; ++r) {
            const int h  = hbase + r;
            const int hb = h << 9;           // h*512 bytes
            const int sw = (h & 7) << 4;
#pragma unroll
            for (int ni = 0; ni < 4; ++ni) {
                const int g = (wc << 6) + (ni << 4) + l15;
                *(_Float16*)(lds + P_OFF + ((hb + (g << 1)) ^ sw)) =
                    (_Float16)(acc[mi][ni][r] * cinv[ni]);
            }
        }
    }

    // ---------------- phase 3: out = P V (prefetched) ----------------
#pragma unroll
    for (int i = 0; i < 4; ++i)
#pragma unroll
        for (int j = 0; j < 4; ++j) acc[i][j] = fzero;

    for (int gc = 0; gc < 256; gc += 32) {
        __syncthreads();                     // P written / prior Vt reads done
        const _Float16* ve = (const _Float16*)&vd;
#pragma unroll
        for (int j = 0; j < 8; ++j) {
            const int w  = (wo << 3) + j;
            const int fw = ((w & 7) ^ ((w >> 3) & 7)) << 4;
            *(_Float16*)(lds + B_OFF + (((w << 6) + (gg << 1)) ^ fw)) = ve[j];
        }
        if (gc < 224)                        // issue next V chunk early
            vd = *(const uint4*)(Vh + vg + (size_t)(gc + 32) * 256);
        __syncthreads();

        f16x8 bf[4];
#pragma unroll
        for (int ni = 0; ni < 4; ++ni) {
            const int w  = (wc << 6) + (ni << 4) + l15;
            const int fw = ((w & 7) ^ ((w >> 3) & 7)) << 4;
            bf[ni] = *(const f16x8*)(lds + B_OFF + (((w << 6) + (q4 << 4)) ^ fw));
        }
#pragma unroll
        for (int mi = 0; mi < 4; ++mi) {
            const int h = (wr << 6) + (mi << 4) + l15;
            const f16x8 af = *(const f16x8*)(lds + P_OFF +
                (((h << 9) + ((gc + (q4 << 3)) << 1)) ^ ((h & 7) << 4)));
#pragma unroll
            for (int ni = 0; ni < 4; ++ni)
                acc[mi][ni] = __builtin_amdgcn_mfma_f32_16x16x32_f16(af, bf[ni], acc[mi][ni], 0, 0, 0);
        }
    }

    // ---------------- store out (fp32) ----------------
    float* op = out + base;
#pragma unroll
    for (int mi = 0; mi < 4; ++mi) {
#pragma unroll
        for (int r = 0; r < 4; ++r) {
            const int h = (wr << 6) + (mi << 4) + (q4 << 2) + r;
#pragma unroll
            for (int ni = 0; ni < 4; ++ni) {
                const int w = (wc << 6) + (ni << 4) + l15;
                op[(h << 8) + w] = acc[mi][ni][r];
            }
        }
    }
}

// ---------------------------------------------------------------------------
extern "C" void kernel_launch(void* const* d_in, const int* in_sizes, int n_in,
                              void* d_out, int out_size, void* d_ws, size_t ws_size,
                              hipStream_t stream) {
    const float* x     = (const float*)d_in[0];
    const float* wq    = (const float*)d_in[1];
    const float* bq    = (const float*)d_in[2];
    const float* wk    = (const float*)d_in[3];
    const float* bk    = (const float*)d_in[4];
    const float* wv    = (const float*)d_in[5];
    const float* bv    = (const float*)d_in[6];
    const float* gamma = (const float*)d_in[7];
    float* out = (float*)d_out;

    // workspace: Q,K,V fp16, each 512*65536 elements = 64 MiB -> 192 MiB total
    _Float16* Qh = (_Float16*)d_ws;
    _Float16* Kh = Qh + (size_t)512 * 65536;
    _Float16* Vh = Kh + (size_t)512 * 65536;

    proj_qkv_mfma<<<4096, 256, 0, stream>>>(x, wq, bq, wk, bk, wv, bv, Qh, Kh, Vh);
    attn_rowsm<<<512, 1024, 0, stream>>>(Qh, Kh, Vh, gamma, out);
}